// Round 3
// baseline (38.260 us; speedup 1.0000x reference)
//
#include <hip/hip_runtime.h>

typedef float f4 __attribute__((ext_vector_type(4)));

// Workspace float layout:
#define NF_W1P  0      // 32   W1 block partial sums
#define NF_W2P  32     // 96   W2 block partial sums
#define NF_B1   128    // 1    sum(b1)
#define NF_B2   129    // 1    sum(b2)
#define NF_S0   130    // 512  s0[b*64+l] = sum_d z1[b,l,d]
#define NF_CW3P 656    // 8*768 W3 column-sum partials (8 row-groups of 96)
#define NF_CW3  6800   // 768  final colsum(W3)
#define NF_U    7568   // 512  final u[b*64+l]
#define NI_CNT  8080   // int: completion counter (memset to 0 each launch)

__device__ __forceinline__ float wave_reduce(float v) {
#pragma unroll
    for (int off = 32; off; off >>= 1) v += __shfl_down(v, off, 64);
    return v;
}

__device__ __forceinline__ float block_reduce_256(float v) {
    __shared__ float sm[4];
    v = wave_reduce(v);
    int lane = threadIdx.x & 63, wid = threadIdx.x >> 6;
    if (lane == 0) sm[wid] = v;
    __syncthreads();
    if (threadIdx.x == 0) v = sm[0] + sm[1] + sm[2] + sm[3];
    return v;
}

// 282 blocks x 256 threads; fixed partition -> deterministic sums.
// Tail: last block to finish folds partials into final cw3[768] and u[512]
// (fold order is fixed, so the result is identical whichever block is last).
__global__ __launch_bounds__(256) void k_reduce(
    const float* __restrict__ z1, const float* __restrict__ W1,
    const float* __restrict__ b1, const float* __restrict__ W2,
    const float* __restrict__ b2, const float* __restrict__ W3,
    float* __restrict__ f) {
    const int blk = blockIdx.x, tid = threadIdx.x;
    if (blk < 128) {
        // blocks 0..31: W1 (32 x 4096), blocks 32..127: W2 (96 x 4096)
        const float* p = (blk < 32) ? (W1 + blk * 4096) : (W2 + (blk - 32) * 4096);
        float s = 0.f;
#pragma unroll
        for (int i = 0; i < 16; ++i) s += p[tid + i * 256];
        s = block_reduce_256(s);
        if (tid == 0) f[blk] = s;
    } else if (blk == 128) {
        float s = b1[tid] + b1[tid + 256];
        s = block_reduce_256(s);
        if (tid == 0) f[NF_B1] = s;
    } else if (blk == 129) {
        float s = b2[tid] + b2[tid + 256] + b2[tid + 512];
        s = block_reduce_256(s);
        if (tid == 0) f[NF_B2] = s;
    } else if (blk < 258) {
        // s0: one wave per (b,l) row, 4 rows/block
        const int lane = tid & 63, wid = tid >> 6;
        const int row = (blk - 130) * 4 + wid;
        const float* p = z1 + row * 256;
        float s = p[lane] + p[lane + 64] + p[lane + 128] + p[lane + 192];
        s = wave_reduce(s);
        if (lane == 0) f[NF_S0 + row] = s;
    } else {
        // W3 column partials: 24 blocks = 3 col-groups x 8 row-groups of 96
        const int g = blk - 258;
        const int cg = g % 3, rg = g / 3;
        const int e = cg * 256 + tid;
        const float* p = W3 + rg * 96 * 768 + e;
        float s = 0.f;
#pragma unroll 8
        for (int d = 0; d < 96; ++d) s += p[d * 768];
        f[NF_CW3P + rg * 768 + e] = s;
    }

    // ---- last-block combine ----
    __shared__ int last_sm;
    __shared__ float s12_sm[2];
    __syncthreads();                       // all of this block's stores issued
    if (tid == 0) {
        __threadfence();                   // release: publish our partials
        int old = atomicAdd((int*)(f + NI_CNT), 1);
        last_sm = (old == 281);
    }
    __syncthreads();
    if (!last_sm) return;
    __threadfence();                       // acquire: see all partials

    // cw3 final (768 cols, fixed fold order)
#pragma unroll
    for (int k = 0; k < 3; ++k) {
        const int e = tid + k * 256;
        float c = 0.f;
#pragma unroll
        for (int r = 0; r < 8; ++r) c += f[NF_CW3P + r * 768 + e];
        f[NF_CW3 + e] = c;
    }
    // S1 (32 partials), S2 (96 partials) in wave 0
    if (tid < 64) {
        float a = (tid < 32) ? f[NF_W1P + tid] : 0.f;
        float b = f[NF_W2P + tid] + ((tid < 32) ? f[NF_W2P + 64 + tid] : 0.f);
#pragma unroll
        for (int off = 32; off; off >>= 1) {
            a += __shfl_down(a, off, 64);
            b += __shfl_down(b, off, 64);
        }
        if (tid == 0) { s12_sm[0] = a; s12_sm[1] = b; }
    }
    __syncthreads();
    const float S1 = s12_sm[0], S2 = s12_sm[1];
    const float B1 = f[NF_B1], B2 = f[NF_B2];
#pragma unroll
    for (int k = 0; k < 2; ++k) {
        const int t = tid + k * 256;
        // 65536 = 256^2 channel-sum cascade (exact pow2 scale)
        f[NF_U + t] = (65536.0f * f[NF_S0 + t] * S1 + B1) * S2 + B2;
    }
}

// out[b,t,e] = u[b, t>>6] * cw3[e] + b3[e].
// Grid 2048 x 256: 16 rows/block, all sharing one u -> compute the 768-float
// row value once per lane (3 fma4), then 12 pure nontemporal stores.
__global__ __launch_bounds__(256) void k_write(
    const float* __restrict__ f, const float* __restrict__ b3,
    float* __restrict__ out) {
    const int tid = threadIdx.x;
    const int lane = tid & 63, wid = tid >> 6;
    const float u = f[NF_U + (blockIdx.x >> 2)];   // 4 blocks per 64-row group
    const f4* __restrict__ cw4 = (const f4*)(f + NF_CW3);
    const f4* __restrict__ b4  = (const f4*)b3;
    f4 v[3];
#pragma unroll
    for (int k = 0; k < 3; ++k) {
        const int e4 = lane + k * 64;
        const f4 c = cw4[e4];
        const f4 b = b4[e4];
        v[k].x = fmaf(u, c.x, b.x);
        v[k].y = fmaf(u, c.y, b.y);
        v[k].z = fmaf(u, c.z, b.z);
        v[k].w = fmaf(u, c.w, b.w);
    }
#pragma unroll
    for (int r = 0; r < 4; ++r) {
        const int row = blockIdx.x * 16 + wid * 4 + r;
        f4* o = (f4*)(out + (size_t)row * 768);
#pragma unroll
        for (int k = 0; k < 3; ++k)
            __builtin_nontemporal_store(v[k], &o[lane + k * 64]);
    }
}

extern "C" void kernel_launch(void* const* d_in, const int* in_sizes, int n_in,
                              void* d_out, int out_size, void* d_ws, size_t ws_size,
                              hipStream_t stream) {
    const float* z1 = (const float*)d_in[0];
    const float* W1 = (const float*)d_in[1];
    const float* b1 = (const float*)d_in[2];
    const float* W2 = (const float*)d_in[3];
    const float* b2 = (const float*)d_in[4];
    const float* W3 = (const float*)d_in[5];
    const float* b3 = (const float*)d_in[6];
    float* out = (float*)d_out;
    float* f = (float*)d_ws;   // needs 32324 bytes

    // zero the completion counter (ws is poisoned 0xAA, never re-zeroed)
    hipMemsetAsync((char*)d_ws + NI_CNT * sizeof(float), 0, 4, stream);
    k_reduce<<<282, 256, 0, stream>>>(z1, W1, b1, W2, b2, W3, f);
    k_write<<<2048, 256, 0, stream>>>(f, b3, out);
}

// Round 4
// 29.401 us; speedup vs baseline: 1.3013x; 1.3013x over previous
//
#include <hip/hip_runtime.h>

typedef float f4 __attribute__((ext_vector_type(4)));

// Workspace float layout:
#define NF_W1P  0      // 32   W1 block partial sums
#define NF_W2P  32     // 96   W2 block partial sums
#define NF_B1   128    // 1    sum(b1)
#define NF_B2   129    // 1    sum(b2)
#define NF_S0   130    // 512  s0[b*64+l] = sum_d z1[b,l,d]
#define NF_CW3P 656    // 8*768 W3 column-sum partials (8 row-groups of 96)
#define NF_CW3  6800   // 768  final colsum(W3)
#define NF_U    7568   // 512  final u[b*64+l]

__device__ __forceinline__ float wave_reduce(float v) {
#pragma unroll
    for (int off = 32; off; off >>= 1) v += __shfl_down(v, off, 64);
    return v;
}

__device__ __forceinline__ float block_reduce_256(float v) {
    __shared__ float sm[4];
    v = wave_reduce(v);
    int lane = threadIdx.x & 63, wid = threadIdx.x >> 6;
    if (lane == 0) sm[wid] = v;
    __syncthreads();
    if (threadIdx.x == 0) v = sm[0] + sm[1] + sm[2] + sm[3];
    return v;
}

// 282 blocks x 256 threads; fixed partition -> deterministic sums.
__global__ __launch_bounds__(256) void k_reduce(
    const float* __restrict__ z1, const float* __restrict__ W1,
    const float* __restrict__ b1, const float* __restrict__ W2,
    const float* __restrict__ b2, const float* __restrict__ W3,
    float* __restrict__ f) {
    const int blk = blockIdx.x, tid = threadIdx.x;
    if (blk < 128) {
        // blocks 0..31: W1 (32 x 4096), blocks 32..127: W2 (96 x 4096)
        const float* p = (blk < 32) ? (W1 + blk * 4096) : (W2 + (blk - 32) * 4096);
        float s = 0.f;
#pragma unroll
        for (int i = 0; i < 16; ++i) s += p[tid + i * 256];
        s = block_reduce_256(s);
        if (tid == 0) f[blk] = s;
    } else if (blk == 128) {
        float s = b1[tid] + b1[tid + 256];
        s = block_reduce_256(s);
        if (tid == 0) f[NF_B1] = s;
    } else if (blk == 129) {
        float s = b2[tid] + b2[tid + 256] + b2[tid + 512];
        s = block_reduce_256(s);
        if (tid == 0) f[NF_B2] = s;
    } else if (blk < 258) {
        // s0: one wave per (b,l) row, 4 rows/block
        const int lane = tid & 63, wid = tid >> 6;
        const int row = (blk - 130) * 4 + wid;
        const float* p = z1 + row * 256;
        float s = p[lane] + p[lane + 64] + p[lane + 128] + p[lane + 192];
        s = wave_reduce(s);
        if (lane == 0) f[NF_S0 + row] = s;
    } else {
        // W3 column partials: 24 blocks = 3 col-groups x 8 row-groups of 96
        const int g = blk - 258;
        const int cg = g % 3, rg = g / 3;
        const int e = cg * 256 + tid;
        const float* p = W3 + rg * 96 * 768 + e;
        float s = 0.f;
#pragma unroll 8
        for (int d = 0; d < 96; ++d) s += p[d * 768];
        f[NF_CW3P + rg * 768 + e] = s;
    }
}

// 1 block x 768 threads: fold partials into cw3[768] and u[512].
__global__ __launch_bounds__(768) void k_combine(float* __restrict__ f) {
    __shared__ float s12_sm[2];
    const int tid = threadIdx.x;
    float c = 0.f;
#pragma unroll
    for (int r = 0; r < 8; ++r) c += f[NF_CW3P + r * 768 + tid];
    f[NF_CW3 + tid] = c;
    if (tid < 64) {
        float a = (tid < 32) ? f[NF_W1P + tid] : 0.f;
        float b = f[NF_W2P + tid] + ((tid < 32) ? f[NF_W2P + 64 + tid] : 0.f);
#pragma unroll
        for (int off = 32; off; off >>= 1) {
            a += __shfl_down(a, off, 64);
            b += __shfl_down(b, off, 64);
        }
        if (tid == 0) { s12_sm[0] = a; s12_sm[1] = b; }
    }
    __syncthreads();
    if (tid < 512) {
        const float S1 = s12_sm[0], S2 = s12_sm[1];
        // 65536 = 256^2 channel-sum cascade (exact pow2 scale)
        f[NF_U + tid] = (65536.0f * f[NF_S0 + tid] * S1 + f[NF_B1]) * S2 + f[NF_B2];
    }
}

// out[b,t,e] = u[b, t>>6] * cw3[e] + b3[e].
// Grid 2048 x 256: 16 rows/block sharing one u -> compute the 768-float row
// once per lane (3 fma4), then 12 pure nontemporal stores. No LDS, no syncs.
__global__ __launch_bounds__(256) void k_write(
    const float* __restrict__ f, const float* __restrict__ b3,
    float* __restrict__ out) {
    const int tid = threadIdx.x;
    const int lane = tid & 63, wid = tid >> 6;
    const float u = f[NF_U + (blockIdx.x >> 2)];   // 4 blocks per 64-row group
    const f4* __restrict__ cw4 = (const f4*)(f + NF_CW3);
    const f4* __restrict__ b4  = (const f4*)b3;
    f4 v[3];
#pragma unroll
    for (int k = 0; k < 3; ++k) {
        const int e4 = lane + k * 64;
        const f4 c = cw4[e4];
        const f4 b = b4[e4];
        v[k].x = fmaf(u, c.x, b.x);
        v[k].y = fmaf(u, c.y, b.y);
        v[k].z = fmaf(u, c.z, b.z);
        v[k].w = fmaf(u, c.w, b.w);
    }
#pragma unroll
    for (int r = 0; r < 4; ++r) {
        const int row = blockIdx.x * 16 + wid * 4 + r;
        f4* o = (f4*)(out + (size_t)row * 768);
#pragma unroll
        for (int k = 0; k < 3; ++k)
            __builtin_nontemporal_store(v[k], &o[lane + k * 64]);
    }
}

extern "C" void kernel_launch(void* const* d_in, const int* in_sizes, int n_in,
                              void* d_out, int out_size, void* d_ws, size_t ws_size,
                              hipStream_t stream) {
    const float* z1 = (const float*)d_in[0];
    const float* W1 = (const float*)d_in[1];
    const float* b1 = (const float*)d_in[2];
    const float* W2 = (const float*)d_in[3];
    const float* b2 = (const float*)d_in[4];
    const float* W3 = (const float*)d_in[5];
    const float* b3 = (const float*)d_in[6];
    float* out = (float*)d_out;
    float* f = (float*)d_ws;   // needs 32320 bytes

    k_reduce<<<282, 256, 0, stream>>>(z1, W1, b1, W2, b2, W3, f);
    k_combine<<<1, 768, 0, stream>>>(f);
    k_write<<<2048, 256, 0, stream>>>(f, b3, out);
}

// Round 5
// 28.037 us; speedup vs baseline: 1.3647x; 1.0487x over previous
//
#include <hip/hip_runtime.h>

typedef float f4 __attribute__((ext_vector_type(4)));

// Workspace float layout (1424 floats = 5696 bytes):
#define NF_W1P  0      // 32   W1 block partial sums
#define NF_W2P  32     // 96   W2 block partial sums
#define NF_B1   128    // 1    sum(b1)
#define NF_B2   129    // 1    sum(b2)
#define NF_S0   130    // 512  s0[b*64+l] = sum_d z1[b,l,d]
#define NF_CW3  656    // 768  FINAL colsum(W3)

__device__ __forceinline__ float wave_reduce(float v) {
#pragma unroll
    for (int off = 32; off; off >>= 1) v += __shfl_down(v, off, 64);
    return v;
}

__device__ __forceinline__ float block_reduce_256(float v) {
    __shared__ float sm[4];
    v = wave_reduce(v);
    int lane = threadIdx.x & 63, wid = threadIdx.x >> 6;
    if (lane == 0) sm[wid] = v;
    __syncthreads();
    if (threadIdx.x == 0) v = sm[0] + sm[1] + sm[2] + sm[3];
    return v;
}

// 282 blocks x 256 threads; fixed partition -> deterministic sums.
// Emits: W1/W2 partials, B1, B2, s0[512], and FINAL cw3[768].
__global__ __launch_bounds__(256) void k_reduce(
    const float* __restrict__ z1, const float* __restrict__ W1,
    const float* __restrict__ b1, const float* __restrict__ W2,
    const float* __restrict__ b2, const float* __restrict__ W3,
    float* __restrict__ f) {
    const int blk = blockIdx.x, tid = threadIdx.x;
    if (blk < 128) {
        // blocks 0..31: W1 (32 x 4096 floats), 32..127: W2 (96 x 4096)
        const f4* p = (blk < 32) ? (const f4*)(W1 + blk * 4096)
                                 : (const f4*)(W2 + (blk - 32) * 4096);
        f4 a = p[tid] + p[tid + 256] + p[tid + 512] + p[tid + 768];
        float s = block_reduce_256(a.x + a.y + a.z + a.w);
        if (tid == 0) f[blk] = s;
    } else if (blk == 128) {
        float s = 0.f;
        if (tid < 128) { f4 a = ((const f4*)b1)[tid]; s = a.x + a.y + a.z + a.w; }
        s = block_reduce_256(s);
        if (tid == 0) f[NF_B1] = s;
    } else if (blk == 129) {
        float s = 0.f;
        if (tid < 192) { f4 a = ((const f4*)b2)[tid]; s = a.x + a.y + a.z + a.w; }
        s = block_reduce_256(s);
        if (tid == 0) f[NF_B2] = s;
    } else if (blk < 258) {
        // s0: one wave per (b,l) row, 4 rows/block
        const int lane = tid & 63, wid = tid >> 6;
        const int row = (blk - 130) * 4 + wid;
        f4 a = ((const f4*)(z1 + row * 256))[lane];
        float s = wave_reduce(a.x + a.y + a.z + a.w);
        if (lane == 0) f[NF_S0 + row] = s;
    } else {
        // cw3 FINAL: 24 blocks x 32 complete columns each.
        // thread (rg=tid>>5, c=tid&31): sum rows rg*96..rg*96+95 of col g*32+c.
        const int g = blk - 258;                 // 0..23
        const int c = tid & 31, rg = tid >> 5;   // 32 cols x 8 row-groups
        const float* p = W3 + (rg * 96) * 768 + g * 32 + c;
        float s = 0.f;
#pragma unroll 8
        for (int i = 0; i < 96; ++i) s += p[i * 768];
        __shared__ float sm[8][32];
        sm[rg][c] = s;
        __syncthreads();
        if (tid < 32) {                          // fixed fold order
            float acc = 0.f;
#pragma unroll
            for (int r = 0; r < 8; ++r) acc += sm[r][tid];
            f[NF_CW3 + g * 32 + tid] = acc;
        }
    }
}

// out[b,t,e] = u[b, t>>6] * cw3[e] + b3[e].
// Grid 2048 x 256: wave 0 folds S1(32)+S2(96) and computes u while the
// block's cw/b3 loads are in flight; then 16 rows/block of pure NT stores.
__global__ __launch_bounds__(256) void k_write(
    const float* __restrict__ f, const float* __restrict__ b3,
    float* __restrict__ out) {
    const int tid = threadIdx.x;
    const int lane = tid & 63, wid = tid >> 6;

    // Issue independent loads first (hide the wave-0 fold under them).
    const f4* __restrict__ cw4 = (const f4*)(f + NF_CW3);
    const f4* __restrict__ b4  = (const f4*)b3;
    f4 c[3], b[3];
#pragma unroll
    for (int k = 0; k < 3; ++k) {
        c[k] = cw4[lane + k * 64];
        b[k] = b4[lane + k * 64];
    }

    __shared__ float u_sm;
    if (tid < 64) {
        float a = (lane < 32) ? f[NF_W1P + lane] : 0.f;
        float w = f[NF_W2P + lane] + ((lane < 32) ? f[NF_W2P + 64 + lane] : 0.f);
#pragma unroll
        for (int off = 32; off; off >>= 1) {
            a += __shfl_down(a, off, 64);
            w += __shfl_down(w, off, 64);
        }
        if (lane == 0) {
            // 65536 = 256^2 channel-sum cascade (exact pow2 scale)
            const float s0v = f[NF_S0 + (blockIdx.x >> 2)];
            u_sm = (65536.0f * s0v * a + f[NF_B1]) * w + f[NF_B2];
        }
    }
    __syncthreads();
    const float u = u_sm;

    f4 v[3];
#pragma unroll
    for (int k = 0; k < 3; ++k) {
        v[k].x = fmaf(u, c[k].x, b[k].x);
        v[k].y = fmaf(u, c[k].y, b[k].y);
        v[k].z = fmaf(u, c[k].z, b[k].z);
        v[k].w = fmaf(u, c[k].w, b[k].w);
    }
#pragma unroll
    for (int r = 0; r < 4; ++r) {
        const int row = blockIdx.x * 16 + wid * 4 + r;
        f4* o = (f4*)(out + (size_t)row * 768);
#pragma unroll
        for (int k = 0; k < 3; ++k)
            __builtin_nontemporal_store(v[k], &o[lane + k * 64]);
    }
}

extern "C" void kernel_launch(void* const* d_in, const int* in_sizes, int n_in,
                              void* d_out, int out_size, void* d_ws, size_t ws_size,
                              hipStream_t stream) {
    const float* z1 = (const float*)d_in[0];
    const float* W1 = (const float*)d_in[1];
    const float* b1 = (const float*)d_in[2];
    const float* W2 = (const float*)d_in[3];
    const float* b2 = (const float*)d_in[4];
    const float* W3 = (const float*)d_in[5];
    const float* b3 = (const float*)d_in[6];
    float* out = (float*)d_out;
    float* f = (float*)d_ws;   // needs 5696 bytes

    k_reduce<<<282, 256, 0, stream>>>(z1, W1, b1, W2, b2, W3, f);
    k_write<<<2048, 256, 0, stream>>>(f, b3, out);
}

// Round 6
// 27.968 us; speedup vs baseline: 1.3680x; 1.0025x over previous
//
#include <hip/hip_runtime.h>

typedef float f4 __attribute__((ext_vector_type(4)));

// Workspace float layout (1424 floats = 5696 bytes):
#define NF_W1P  0      // 32   W1 block partial sums
#define NF_W2P  32     // 96   W2 block partial sums
#define NF_B1   128    // 1    sum(b1)
#define NF_B2   129    // 1    sum(b2)
#define NF_S0   130    // 512  s0[b*64+l] = sum_d z1[b,l,d]
#define NF_CW3  656    // 768  FINAL colsum(W3)

__device__ __forceinline__ float wave_reduce(float v) {
#pragma unroll
    for (int off = 32; off; off >>= 1) v += __shfl_down(v, off, 64);
    return v;
}

__device__ __forceinline__ float block_reduce_256(float v) {
    __shared__ float sm[4];
    v = wave_reduce(v);
    int lane = threadIdx.x & 63, wid = threadIdx.x >> 6;
    if (lane == 0) sm[wid] = v;
    __syncthreads();
    if (threadIdx.x == 0) v = sm[0] + sm[1] + sm[2] + sm[3];
    return v;
}

// 282 blocks x 256 threads; fixed partition -> deterministic sums.
// Emits: W1/W2 partials, B1, B2, s0[512], and FINAL cw3[768].
__global__ __launch_bounds__(256) void k_reduce(
    const float* __restrict__ z1, const float* __restrict__ W1,
    const float* __restrict__ b1, const float* __restrict__ W2,
    const float* __restrict__ b2, const float* __restrict__ W3,
    float* __restrict__ f) {
    const int blk = blockIdx.x, tid = threadIdx.x;
    if (blk < 128) {
        // blocks 0..31: W1 (32 x 4096 floats), 32..127: W2 (96 x 4096)
        const f4* p = (blk < 32) ? (const f4*)(W1 + blk * 4096)
                                 : (const f4*)(W2 + (blk - 32) * 4096);
        f4 a = p[tid] + p[tid + 256] + p[tid + 512] + p[tid + 768];
        float s = block_reduce_256(a.x + a.y + a.z + a.w);
        if (tid == 0) f[blk] = s;
    } else if (blk == 128) {
        float s = 0.f;
        if (tid < 128) { f4 a = ((const f4*)b1)[tid]; s = a.x + a.y + a.z + a.w; }
        s = block_reduce_256(s);
        if (tid == 0) f[NF_B1] = s;
    } else if (blk == 129) {
        float s = 0.f;
        if (tid < 192) { f4 a = ((const f4*)b2)[tid]; s = a.x + a.y + a.z + a.w; }
        s = block_reduce_256(s);
        if (tid == 0) f[NF_B2] = s;
    } else if (blk < 258) {
        // s0: one wave per (b,l) row, 4 rows/block
        const int lane = tid & 63, wid = tid >> 6;
        const int row = (blk - 130) * 4 + wid;
        f4 a = ((const f4*)(z1 + row * 256))[lane];
        float s = wave_reduce(a.x + a.y + a.z + a.w);
        if (lane == 0) f[NF_S0 + row] = s;
    } else {
        // cw3 FINAL: 24 blocks x 32 cols (8 f4-cols). Thread (fc=tid&7,
        // rg=tid>>3): f4-accumulate 24 rows of f4-col g*8+fc. A wave's 64
        // lanes cover 8 f4-cols (128B contiguous) x 8 row-groups -> perfect
        // coalescing; 24 loads all in flight (latency ~1 batch).
        const int g = blk - 258;                 // 0..23
        const int fc = tid & 7, rg = tid >> 3;   // 8 f4-cols x 32 row-groups
        const f4* w4 = (const f4*)W3;            // [768][192] f4 view
        const int base = (rg * 24) * 192 + g * 8 + fc;
        f4 acc = {0.f, 0.f, 0.f, 0.f};
#pragma unroll
        for (int i = 0; i < 24; ++i) acc += w4[base + i * 192];
        __shared__ f4 sm[32][8];
        sm[rg][fc] = acc;
        __syncthreads();
        if (tid < 8) {                           // fixed fold order
            f4 a = {0.f, 0.f, 0.f, 0.f};
#pragma unroll
            for (int r = 0; r < 32; ++r) a += sm[r][tid];
            ((f4*)(f + NF_CW3 + g * 32))[tid] = a;
        }
    }
}

// out[b,t,e] = u[b, t>>6] * cw3[e] + b3[e].
// Grid 2048 x 256: wave 0 folds S1(32)+S2(96) and computes u while the
// block's cw/b3 loads are in flight; then 16 rows/block of pure NT stores.
__global__ __launch_bounds__(256) void k_write(
    const float* __restrict__ f, const float* __restrict__ b3,
    float* __restrict__ out) {
    const int tid = threadIdx.x;
    const int lane = tid & 63, wid = tid >> 6;

    // Issue independent loads first (hide the wave-0 fold under them).
    const f4* __restrict__ cw4 = (const f4*)(f + NF_CW3);
    const f4* __restrict__ b4  = (const f4*)b3;
    f4 c[3], b[3];
#pragma unroll
    for (int k = 0; k < 3; ++k) {
        c[k] = cw4[lane + k * 64];
        b[k] = b4[lane + k * 64];
    }

    __shared__ float u_sm;
    if (tid < 64) {
        float a = (lane < 32) ? f[NF_W1P + lane] : 0.f;
        float w = f[NF_W2P + lane] + ((lane < 32) ? f[NF_W2P + 64 + lane] : 0.f);
#pragma unroll
        for (int off = 32; off; off >>= 1) {
            a += __shfl_down(a, off, 64);
            w += __shfl_down(w, off, 64);
        }
        if (lane == 0) {
            // 65536 = 256^2 channel-sum cascade (exact pow2 scale)
            const float s0v = f[NF_S0 + (blockIdx.x >> 2)];
            u_sm = (65536.0f * s0v * a + f[NF_B1]) * w + f[NF_B2];
        }
    }
    __syncthreads();
    const float u = u_sm;

    f4 v[3];
#pragma unroll
    for (int k = 0; k < 3; ++k) {
        v[k].x = fmaf(u, c[k].x, b[k].x);
        v[k].y = fmaf(u, c[k].y, b[k].y);
        v[k].z = fmaf(u, c[k].z, b[k].z);
        v[k].w = fmaf(u, c[k].w, b[k].w);
    }
#pragma unroll
    for (int r = 0; r < 4; ++r) {
        const int row = blockIdx.x * 16 + wid * 4 + r;
        f4* o = (f4*)(out + (size_t)row * 768);
#pragma unroll
        for (int k = 0; k < 3; ++k)
            __builtin_nontemporal_store(v[k], &o[lane + k * 64]);
    }
}

extern "C" void kernel_launch(void* const* d_in, const int* in_sizes, int n_in,
                              void* d_out, int out_size, void* d_ws, size_t ws_size,
                              hipStream_t stream) {
    const float* z1 = (const float*)d_in[0];
    const float* W1 = (const float*)d_in[1];
    const float* b1 = (const float*)d_in[2];
    const float* W2 = (const float*)d_in[3];
    const float* b2 = (const float*)d_in[4];
    const float* W3 = (const float*)d_in[5];
    const float* b3 = (const float*)d_in[6];
    float* out = (float*)d_out;
    float* f = (float*)d_ws;   // needs 5696 bytes

    k_reduce<<<282, 256, 0, stream>>>(z1, W1, b1, W2, b2, W3, f);
    k_write<<<2048, 256, 0, stream>>>(f, b3, out);
}

// Round 7
// 27.181 us; speedup vs baseline: 1.4076x; 1.0290x over previous
//
#include <hip/hip_runtime.h>

typedef float f4 __attribute__((ext_vector_type(4)));

// Workspace float layout (1424 floats = 5696 bytes):
#define NF_W1P  0      // 32   W1 block partial sums
#define NF_W2P  32     // 96   W2 block partial sums
#define NF_B1   128    // 1    sum(b1)
#define NF_B2   129    // 1    sum(b2)
#define NF_S0   130    // 512  s0[b*64+l] = sum_d z1[b,l,d]
#define NF_CW3  656    // 768  FINAL colsum(W3)

__device__ __forceinline__ float wave_reduce(float v) {
#pragma unroll
    for (int off = 32; off; off >>= 1) v += __shfl_down(v, off, 64);
    return v;
}

__device__ __forceinline__ float block_reduce_256(float v) {
    __shared__ float sm[4];
    v = wave_reduce(v);
    int lane = threadIdx.x & 63, wid = threadIdx.x >> 6;
    if (lane == 0) sm[wid] = v;
    __syncthreads();
    if (threadIdx.x == 0) v = sm[0] + sm[1] + sm[2] + sm[3];
    return v;
}

// 282 blocks x 256 threads; fixed partition -> deterministic sums.
// Emits: W1/W2 partials, B1, B2, s0[512], and FINAL cw3[768].
__global__ __launch_bounds__(256) void k_reduce(
    const float* __restrict__ z1, const float* __restrict__ W1,
    const float* __restrict__ b1, const float* __restrict__ W2,
    const float* __restrict__ b2, const float* __restrict__ W3,
    float* __restrict__ f) {
    const int blk = blockIdx.x, tid = threadIdx.x;
    if (blk < 128) {
        // blocks 0..31: W1 (32 x 4096 floats), 32..127: W2 (96 x 4096)
        const f4* p = (blk < 32) ? (const f4*)(W1 + blk * 4096)
                                 : (const f4*)(W2 + (blk - 32) * 4096);
        f4 a = p[tid] + p[tid + 256] + p[tid + 512] + p[tid + 768];
        float s = block_reduce_256(a.x + a.y + a.z + a.w);
        if (tid == 0) f[blk] = s;
    } else if (blk == 128) {
        float s = 0.f;
        if (tid < 128) { f4 a = ((const f4*)b1)[tid]; s = a.x + a.y + a.z + a.w; }
        s = block_reduce_256(s);
        if (tid == 0) f[NF_B1] = s;
    } else if (blk == 129) {
        float s = 0.f;
        if (tid < 192) { f4 a = ((const f4*)b2)[tid]; s = a.x + a.y + a.z + a.w; }
        s = block_reduce_256(s);
        if (tid == 0) f[NF_B2] = s;
    } else if (blk < 258) {
        // s0: one wave per (b,l) row, 4 rows/block
        const int lane = tid & 63, wid = tid >> 6;
        const int row = (blk - 130) * 4 + wid;
        f4 a = ((const f4*)(z1 + row * 256))[lane];
        float s = wave_reduce(a.x + a.y + a.z + a.w);
        if (lane == 0) f[NF_S0 + row] = s;
    } else {
        // cw3 FINAL: 24 blocks x 32 cols (8 f4-cols). Thread (fc=tid&7,
        // rg=tid>>3): f4-accumulate 24 rows of f4-col g*8+fc.
        const int g = blk - 258;                 // 0..23
        const int fc = tid & 7, rg = tid >> 3;   // 8 f4-cols x 32 row-groups
        const f4* w4 = (const f4*)W3;            // [768][192] f4 view
        const int base = (rg * 24) * 192 + g * 8 + fc;
        f4 acc = {0.f, 0.f, 0.f, 0.f};
#pragma unroll
        for (int i = 0; i < 24; ++i) acc += w4[base + i * 192];
        __shared__ f4 sm[32][8];
        sm[rg][fc] = acc;
        __syncthreads();
        if (tid < 8) {                           // fixed fold order
            f4 a = {0.f, 0.f, 0.f, 0.f};
#pragma unroll
            for (int r = 0; r < 32; ++r) a += sm[r][tid];
            ((f4*)(f + NF_CW3 + g * 32))[tid] = a;
        }
    }
}

// out[b,t,e] = u[b, t>>6] * cw3[e] + b3[e].
// Grid 2048 x 256: wave 0 folds S1(32)+S2(96) and computes u while the
// block's cw/b3 loads are in flight; then 16 rows/block of CACHED stores
// (output fits the 256MB LLC -> let it absorb the burst; NT forced HBM rate).
__global__ __launch_bounds__(256) void k_write(
    const float* __restrict__ f, const float* __restrict__ b3,
    float* __restrict__ out) {
    const int tid = threadIdx.x;
    const int lane = tid & 63, wid = tid >> 6;

    // Issue independent loads first (hide the wave-0 fold under them).
    const f4* __restrict__ cw4 = (const f4*)(f + NF_CW3);
    const f4* __restrict__ b4  = (const f4*)b3;
    f4 c[3], b[3];
#pragma unroll
    for (int k = 0; k < 3; ++k) {
        c[k] = cw4[lane + k * 64];
        b[k] = b4[lane + k * 64];
    }

    __shared__ float u_sm;
    if (tid < 64) {
        float a = (lane < 32) ? f[NF_W1P + lane] : 0.f;
        float w = f[NF_W2P + lane] + ((lane < 32) ? f[NF_W2P + 64 + lane] : 0.f);
#pragma unroll
        for (int off = 32; off; off >>= 1) {
            a += __shfl_down(a, off, 64);
            w += __shfl_down(w, off, 64);
        }
        if (lane == 0) {
            // 65536 = 256^2 channel-sum cascade (exact pow2 scale)
            const float s0v = f[NF_S0 + (blockIdx.x >> 2)];
            u_sm = (65536.0f * s0v * a + f[NF_B1]) * w + f[NF_B2];
        }
    }
    __syncthreads();
    const float u = u_sm;

    f4 v[3];
#pragma unroll
    for (int k = 0; k < 3; ++k) {
        v[k].x = fmaf(u, c[k].x, b[k].x);
        v[k].y = fmaf(u, c[k].y, b[k].y);
        v[k].z = fmaf(u, c[k].z, b[k].z);
        v[k].w = fmaf(u, c[k].w, b[k].w);
    }
#pragma unroll
    for (int r = 0; r < 4; ++r) {
        const int row = blockIdx.x * 16 + wid * 4 + r;
        f4* o = (f4*)(out + (size_t)row * 768);
#pragma unroll
        for (int k = 0; k < 3; ++k)
            o[lane + k * 64] = v[k];
    }
}

extern "C" void kernel_launch(void* const* d_in, const int* in_sizes, int n_in,
                              void* d_out, int out_size, void* d_ws, size_t ws_size,
                              hipStream_t stream) {
    const float* z1 = (const float*)d_in[0];
    const float* W1 = (const float*)d_in[1];
    const float* b1 = (const float*)d_in[2];
    const float* W2 = (const float*)d_in[3];
    const float* b2 = (const float*)d_in[4];
    const float* W3 = (const float*)d_in[5];
    const float* b3 = (const float*)d_in[6];
    float* out = (float*)d_out;
    float* f = (float*)d_ws;   // needs 5696 bytes

    k_reduce<<<282, 256, 0, stream>>>(z1, W1, b1, W2, b2, W3, f);
    k_write<<<2048, 256, 0, stream>>>(f, b3, out);
}

// Round 8
// 26.710 us; speedup vs baseline: 1.4324x; 1.0176x over previous
//
#include <hip/hip_runtime.h>

typedef float f4 __attribute__((ext_vector_type(4)));

// Workspace float layout (1424 floats = 5696 bytes):
#define NF_W1P  0      // 32   W1 block partial sums
#define NF_W2P  32     // 96   W2 block partial sums
#define NF_B1   128    // 1    sum(b1)
#define NF_B2   129    // 1    sum(b2)
#define NF_S0   130    // 512  s0[b*64+l] = sum_d z1[b,l,d]
#define NF_CW3  656    // 768  FINAL colsum(W3)

__device__ __forceinline__ float wave_reduce(float v) {
#pragma unroll
    for (int off = 32; off; off >>= 1) v += __shfl_down(v, off, 64);
    return v;
}

__device__ __forceinline__ float block_reduce_256(float v) {
    __shared__ float sm[4];
    v = wave_reduce(v);
    int lane = threadIdx.x & 63, wid = threadIdx.x >> 6;
    if (lane == 0) sm[wid] = v;
    __syncthreads();
    if (threadIdx.x == 0) v = sm[0] + sm[1] + sm[2] + sm[3];
    return v;
}

// 282 blocks x 256 threads; fixed partition -> deterministic sums.
// Emits: W1/W2 partials, B1, B2, s0[512], and FINAL cw3[768].
__global__ __launch_bounds__(256) void k_reduce(
    const float* __restrict__ z1, const float* __restrict__ W1,
    const float* __restrict__ b1, const float* __restrict__ W2,
    const float* __restrict__ b2, const float* __restrict__ W3,
    float* __restrict__ f) {
    const int blk = blockIdx.x, tid = threadIdx.x;
    if (blk < 128) {
        // blocks 0..31: W1 (32 x 4096 floats), 32..127: W2 (96 x 4096)
        const f4* p = (blk < 32) ? (const f4*)(W1 + blk * 4096)
                                 : (const f4*)(W2 + (blk - 32) * 4096);
        f4 a = p[tid] + p[tid + 256] + p[tid + 512] + p[tid + 768];
        float s = block_reduce_256(a.x + a.y + a.z + a.w);
        if (tid == 0) f[blk] = s;
    } else if (blk == 128) {
        float s = 0.f;
        if (tid < 128) { f4 a = ((const f4*)b1)[tid]; s = a.x + a.y + a.z + a.w; }
        s = block_reduce_256(s);
        if (tid == 0) f[NF_B1] = s;
    } else if (blk == 129) {
        float s = 0.f;
        if (tid < 192) { f4 a = ((const f4*)b2)[tid]; s = a.x + a.y + a.z + a.w; }
        s = block_reduce_256(s);
        if (tid == 0) f[NF_B2] = s;
    } else if (blk < 258) {
        // s0: one wave per (b,l) row, 4 rows/block
        const int lane = tid & 63, wid = tid >> 6;
        const int row = (blk - 130) * 4 + wid;
        f4 a = ((const f4*)(z1 + row * 256))[lane];
        float s = wave_reduce(a.x + a.y + a.z + a.w);
        if (lane == 0) f[NF_S0 + row] = s;
    } else {
        // cw3 FINAL: 24 blocks x 32 cols (8 f4-cols). Thread (fc=tid&7,
        // rg=tid>>3): f4-accumulate 24 rows of f4-col g*8+fc.
        const int g = blk - 258;                 // 0..23
        const int fc = tid & 7, rg = tid >> 3;   // 8 f4-cols x 32 row-groups
        const f4* w4 = (const f4*)W3;            // [768][192] f4 view
        const int base = (rg * 24) * 192 + g * 8 + fc;
        f4 acc = {0.f, 0.f, 0.f, 0.f};
#pragma unroll
        for (int i = 0; i < 24; ++i) acc += w4[base + i * 192];
        __shared__ f4 sm[32][8];
        sm[rg][fc] = acc;
        __syncthreads();
        if (tid < 8) {                           // fixed fold order
            f4 a = {0.f, 0.f, 0.f, 0.f};
#pragma unroll
            for (int r = 0; r < 32; ++r) a += sm[r][tid];
            ((f4*)(f + NF_CW3 + g * 32))[tid] = a;
        }
    }
}

// out[b,t,e] = u[b, t>>6] * cw3[e] + b3[e].
// Grid 2048 x 256, 16 rows/block. Each WAVE independently butterfly-folds
// S1(32)+S2(96) (L2-hot broadcast loads) -> no LDS, no __syncthreads; stores
// issue as soon as the 6-step shuffle chain retires.
__global__ __launch_bounds__(256) void k_write(
    const float* __restrict__ f, const float* __restrict__ b3,
    float* __restrict__ out) {
    const int tid = threadIdx.x;
    const int lane = tid & 63, wid = tid >> 6;

    // Issue independent loads first.
    const f4* __restrict__ cw4 = (const f4*)(f + NF_CW3);
    const f4* __restrict__ b4  = (const f4*)b3;
    f4 c[3], b[3];
#pragma unroll
    for (int k = 0; k < 3; ++k) {
        c[k] = cw4[lane + k * 64];
        b[k] = b4[lane + k * 64];
    }

    // Per-wave butterfly fold: every lane ends with full S1, S2.
    float a = (lane < 32) ? f[NF_W1P + lane] : 0.f;
    float w = f[NF_W2P + lane] + ((lane < 32) ? f[NF_W2P + 64 + lane] : 0.f);
#pragma unroll
    for (int off = 32; off; off >>= 1) {
        a += __shfl_xor(a, off, 64);
        w += __shfl_xor(w, off, 64);
    }
    // 65536 = 256^2 channel-sum cascade (exact pow2 scale)
    const float s0v = f[NF_S0 + (blockIdx.x >> 2)];
    const float u = (65536.0f * s0v * a + f[NF_B1]) * w + f[NF_B2];

    f4 v[3];
#pragma unroll
    for (int k = 0; k < 3; ++k) {
        v[k].x = fmaf(u, c[k].x, b[k].x);
        v[k].y = fmaf(u, c[k].y, b[k].y);
        v[k].z = fmaf(u, c[k].z, b[k].z);
        v[k].w = fmaf(u, c[k].w, b[k].w);
    }
#pragma unroll
    for (int r = 0; r < 4; ++r) {
        const int row = blockIdx.x * 16 + wid * 4 + r;
        f4* o = (f4*)(out + (size_t)row * 768);
#pragma unroll
        for (int k = 0; k < 3; ++k)
            o[lane + k * 64] = v[k];
    }
}

extern "C" void kernel_launch(void* const* d_in, const int* in_sizes, int n_in,
                              void* d_out, int out_size, void* d_ws, size_t ws_size,
                              hipStream_t stream) {
    const float* z1 = (const float*)d_in[0];
    const float* W1 = (const float*)d_in[1];
    const float* b1 = (const float*)d_in[2];
    const float* W2 = (const float*)d_in[3];
    const float* b2 = (const float*)d_in[4];
    const float* W3 = (const float*)d_in[5];
    const float* b3 = (const float*)d_in[6];
    float* out = (float*)d_out;
    float* f = (float*)d_ws;   // needs 5696 bytes

    k_reduce<<<282, 256, 0, stream>>>(z1, W1, b1, W2, b2, W3, f);
    k_write<<<2048, 256, 0, stream>>>(f, b3, out);
}